// Round 6
// baseline (105.036 us; speedup 1.0000x reference)
//
#include <hip/hip_runtime.h>
#include <math.h>

#define B_   4
#define H_   496
#define W_   496
#define HW_  (H_ * W_)
#define N_   (B_ * HW_)
#define TPB  256
#define NPT  4                    // consecutive elements per thread (vector loads)
#define EPB  (TPB * NPT)          // 1024 elements per block
#define NBLK (N_ / EPB)           // 961 exactly

static_assert(N_ % EPB == 0, "no tail");
static_assert(HW_ % NPT == 0, "thread quad must not straddle batch b");

// native clang vector types: __builtin_nontemporal_load requires these
// (HIP_vector_type float4/int4 are structs and are rejected).
typedef float f32x4 __attribute__((ext_vector_type(4)));
typedef int   i32x4 __attribute__((ext_vector_type(4)));

union F4 { f32x4 v; float a[4]; };
union I4 { i32x4 v; int   a[4]; };

// LDS XOR swizzle (frame = 28KB block window, byte address in, WORD index out).
// Read pattern: thread t reads b32 at bytes 112t + {0..108}: the 8 lanes
// {t, t+8, ..} that share a bank pre-swizzle differ by 896B = 7*128; since
// 896 is a multiple of 128, (X+896k) has bits[9:7] = X's + 7k (mod 8, exact),
// i.e. 8 DISTINCT 3-bit values -> XOR into bank bits[4:2] spreads them over 8
// distinct bank-quads -> conflict-free b32 reads. Write pattern (b128, lane
// stride 16B over 1024B): XOR permutes 16B granules within each 256B
// quarter-wave span -> still exactly 2 lanes/bank = free (m136). XOR touches
// only byte bits 4..6, so 16B alignment is preserved.
__device__ __forceinline__ int swz(int byte) {
    return (byte ^ ((byte >> 3) & 0x70)) >> 2;   // returns word index
}

// Clip segment (xk,yk)+t*(dx,dy), t in [0,1], against axis box [-hx,hx]x[-hy,hy].
// SELECT-FREE SLAB METHOD: ta=(-h-k)*r, tb=(h-k)*r; min/max routes the
// entering/exiting plane automatically for either direction sign (~16 VALU).
// dx==+-0: r=+-inf -> no constraint when inside, empty when outside; IEEE
// fmin/fmax drop the measure-zero 0*inf NaN corner (same caveat as before).
__device__ __forceinline__ float edge_delta(float xk, float yk,
                                            float rdx, float rdy,
                                            float hx, float hy) {
    const float tax = (-hx - xk) * rdx, tbx = (hx - xk) * rdx;
    const float tay = (-hy - yk) * rdy, tby = (hy - yk) * rdy;
    const float t0 = fmaxf(fmaxf(fminf(tax, tbx), fminf(tay, tby)), 0.f);  // v_max3
    const float t1 = fminf(fminf(fmaxf(tax, tbx), fmaxf(tay, tby)), 1.f);  // v_min3
    return fmaxf(t1 - t0, 0.f);
}

// One element's IoU-loss terms from 7 pred + 7 gt params (gt-local-frame method).
__device__ __forceinline__ void iou_elem(
    float pax, float pay, float paz, float pdx, float pdy, float pdz, float pr,
    float gax, float gay, float gaz, float gdx, float gdy, float gdz, float gr,
    float ip, float m, float& num, float& den)
{
    float sp, cp; __sincosf(pr, &sp, &cp);
    float sg, cg; __sincosf(gr, &sg, &cg);
    const float cth = fmaf(cp, cg,  sp * sg);   // cos(pr-gr)
    const float sth = fmaf(sp, cg, -cp * sg);   // sin(pr-gr)
    const float wx = pax - gax, wy = pay - gay;
    const float cx = fmaf(cg, wx,  sg * wy);
    const float cy = fmaf(cg, wy, -sg * wx);

    const float phx = 0.5f * pdx, phy = 0.5f * pdy;
    const float ghx = 0.5f * gdx, ghy = 0.5f * gdy;

    // pred corners in gt frame: c + R(th)*([+,-,-,+]phx, [+,+,-,-]phy)
    const float a1 = cth * phx, b1 = sth * phx;
    const float a2 = sth * phy, b2 = cth * phy;
    const float e1 = a1 - a2, e2 = a1 + a2;
    const float f1 = b1 + b2, f2 = b1 - b2;
    const float px0 = cx + e1, py0 = cy + f1;
    const float px1 = cx - e2, py1 = cy - f2;
    const float px2 = cx - e1, py2 = cy - f1;
    const float px3 = cx + e2, py3 = cy + f2;

    const float ta1 = a1 + a1, tb1 = b1 + b1;
    const float ta2 = a2 + a2, tb2 = b2 + b2;
    const float ra1 = __builtin_amdgcn_rcpf(ta1);
    const float rb1 = __builtin_amdgcn_rcpf(tb1);
    const float ra2 = __builtin_amdgcn_rcpf(ta2);
    const float rb2 = __builtin_amdgcn_rcpf(tb2);

    // Half 1: pred edges vs gt box. Piece area = Delta * 0.5*cross(p_k, d_k).
    float inter;
    {
        const float d0 = edge_delta(px0, py0, -ra1, -rb1, ghx, ghy);  // d=(-ta1,-tb1)
        const float d1 = edge_delta(px1, py1,  ra2, -rb2, ghx, ghy);  // d=( ta2,-tb2)
        const float d2 = edge_delta(px2, py2,  ra1,  rb1, ghx, ghy);  // d=( ta1, tb1)
        const float d3 = edge_delta(px3, py3, -ra2,  rb2, ghx, ghy);  // d=(-ta2, tb2)
        inter =        d0 * fmaf(a1, py0, -b1 * px0);
        inter = fmaf(  d1, -fmaf(b2, px1,  a2 * py1), inter);
        inter = fmaf(  d2,  fmaf(b1, px2, -a1 * py2), inter);
        inter = fmaf(  d3,  fmaf(b2, px3,  a2 * py3), inter);
    }

    // Half 2: gt edges vs pred box, t computed in pred's frame (t invariant);
    // each axis-aligned gt edge piece contributes ghx*ghy*Delta.
    {
        const float A  = cth * ghx, Dv = sth * ghx;
        const float Bq = sth * ghy, Ev = cth * ghy;
        const float Cc = fmaf(cth, cx,  sth * cy);
        const float Gf = fmaf(sth, cx, -cth * cy);
        const float g1 = A + Bq,  g2 = A - Bq;
        const float h1 = Ev - Dv, h2 = Ev + Dv;
        const float u0 =  g1 - Cc, v0 =  h1 + Gf;
        const float u1 = -g2 - Cc, v1 =  h2 + Gf;
        const float u2 = -g1 - Cc, v2 = -h1 + Gf;
        const float u3 =  g2 - Cc, v3 = -h2 + Gf;

        const float tA = A + A,   tD = Dv + Dv;
        const float tB = Bq + Bq, tE = Ev + Ev;
        const float rA = __builtin_amdgcn_rcpf(tA);
        const float rD = __builtin_amdgcn_rcpf(tD);
        const float rB = __builtin_amdgcn_rcpf(tB);
        const float rE = __builtin_amdgcn_rcpf(tE);

        float sq;
        sq  = edge_delta(u0, v0, -rA,  rD, phx, phy);  // d=(-tA, tD)
        sq += edge_delta(u1, v1, -rB, -rE, phx, phy);  // d=(-tB,-tE)
        sq += edge_delta(u2, v2,  rA, -rD, phx, phy);  // d=( tA,-tD)
        sq += edge_delta(u3, v3,  rB,  rE, phx, phy);  // d=( tB, tE)
        inter = fmaf(ghx * ghy, sq, inter);
    }

    const float za0 = paz - 0.5f * pdz, za1 = paz + 0.5f * pdz;
    const float zb0 = gaz - 0.5f * gdz, zb1 = gaz + 0.5f * gdz;
    const float zo  = fmaxf(fminf(za1, zb1) - fmaxf(za0, zb0), 0.f);
    const float iv  = inter * zo;
    const float va  = pdx * pdy * pdz;
    const float vb  = gdx * gdy * gdz;
    const float iou = __fdividef(iv, va + vb - iv + 1e-7f);
    const float target = 2.f * iou - 1.f;

    num = fmaf(m, fabsf(ip - target), num);
    den += m;
}

// Fused kernel: per-block partials published as self-validating records in ws,
// block NBLK-1 polls + finishes. Record i (2 x 64b): lo=(bits(num) | ~bits(num)<<32),
// hi=(bits(den) | ~bits(den)<<32). Validation low32==~high32 is impossible for
// any constant 32-bit poison pattern, so garbage-initialized ws needs no init.
// Agent-scope atomics: per-XCD L2s are not coherent (guide G16).
//
// box_gt staging is WAVE-PRIVATE (unlike R4's block-wide version): wave w
// loads exactly its own 7168B window (lane L, chunk j -> byte 7168w+1024j+16L,
// coalesced 1KB/instruction, each line touched once -> nontemporal-safe) and
// reads back only its own threads' 112B slices. All transpose traffic is
// intra-wave, so NO __syncthreads is needed -- the wave's own lgkmcnt ordering
// (compiler-inserted) covers the write->read dependency. This removes the 4x
// L1 line-touch amplification of direct 112B-stride AoS loads without R4's
// block-wide barrier serialization.
__global__ __launch_bounds__(TPB, 4) void iou_fused(
    const float* __restrict__ iou_pred,
    const int*   __restrict__ mask,
    const float* __restrict__ box_pred,   // [B,7,H,W]
    const float* __restrict__ box_gt,     // [B,H,W,7]
    unsigned long long* __restrict__ ws,  // [NBLK*2] packed records
    float* __restrict__ out)
{
    __shared__ __align__(16) float gb[EPB * 7];   // 28KB swizzled box_gt window
    __shared__ float rn[4], rd[4];

    const int tid = threadIdx.x;
    const int wv  = tid >> 6;                         // wave id (0..3)
    const int ln  = tid & 63;                         // lane id
    const int n0  = (blockIdx.x * TPB + tid) * NPT;   // 4 consecutive elements
    const int b   = n0 / HW_;
    const int hw  = n0 - b * HW_;                     // NPT-aligned

    // ---- stage this wave's box_gt window (7168B) coalesced -> swizzled LDS ----
    {
        const float* gwin = box_gt + (size_t)blockIdx.x * (EPB * 7);
#pragma unroll
        for (int j = 0; j < 7; ++j) {
            const int byte = 7168 * wv + 1024 * j + 16 * ln;   // block-window byte
            const f32x4 v = __builtin_nontemporal_load((const f32x4*)(gwin + (byte >> 2)));
            *(f32x4*)&gb[swz(byte)] = v;    // 16B-aligned, conflict-free
        }
    }

    // ---- issue remaining global loads (pure single-touch streams -> nt) ----
    const float* bp = box_pred + (size_t)b * 7 * HW_ + hw;
    F4 pc[7];
#pragma unroll
    for (int c = 0; c < 7; ++c)
        pc[c].v = __builtin_nontemporal_load((const f32x4*)(bp + (size_t)c * HW_));
    F4 ip4; ip4.v = __builtin_nontemporal_load((const f32x4*)(iou_pred + n0));
    I4 mk4; mk4.v = __builtin_nontemporal_load((const i32x4*)(mask + n0));

    // NOTE: no __syncthreads -- wave-private staging; compiler orders the
    // wave's ds_write -> ds_read through lgkmcnt (it cannot disprove aliasing).

    // ---- compute 4 elements (gt params read from swizzled LDS) ----
    float num = 0.f, den = 0.f;
    const int tb = 112 * tid;                  // thread byte base in block window
#pragma unroll
    for (int e = 0; e < NPT; ++e) {
        const int eb = tb + 28 * e;            // element byte base
        const float g0 = gb[swz(eb +  0)];
        const float g1 = gb[swz(eb +  4)];
        const float g2 = gb[swz(eb +  8)];
        const float g3 = gb[swz(eb + 12)];
        const float g4 = gb[swz(eb + 16)];
        const float g5 = gb[swz(eb + 20)];
        const float g6 = gb[swz(eb + 24)];
        iou_elem(pc[0].a[e], pc[1].a[e], pc[2].a[e],
                 pc[3].a[e], pc[4].a[e], pc[5].a[e], pc[6].a[e],
                 g0, g1, g2, g3, g4, g5, g6,
                 ip4.a[e], (float)mk4.a[e], num, den);
    }

    // ---- wave(64) then cross-wave reduction ----
#pragma unroll
    for (int off = 32; off > 0; off >>= 1) {
        num += __shfl_down(num, off);
        den += __shfl_down(den, off);
    }
    if ((tid & 63) == 0) { rn[wv] = num; rd[wv] = den; }
    __syncthreads();

    if (blockIdx.x != NBLK - 1) {
        // publish partial (device-visible, self-validating vs any constant poison)
        if (tid == 0) {
            const unsigned long long a = __float_as_uint(rn[0] + rn[1] + rn[2] + rn[3]);
            const unsigned long long d = __float_as_uint(rd[0] + rd[1] + rd[2] + rd[3]);
            unsigned long long* rec = ws + 2u * blockIdx.x;
            __hip_atomic_store(rec + 0, a | (~a << 32), __ATOMIC_RELAXED, __HIP_MEMORY_SCOPE_AGENT);
            __hip_atomic_store(rec + 1, d | (~d << 32), __ATOMIC_RELAXED, __HIP_MEMORY_SCOPE_AGENT);
        }
        return;
    }

    // ---- finalizer block: seed with own partial, poll the other NBLK-1 ----
    float sn = 0.f, sd = 0.f;
    if (tid == 0) { sn = rn[0] + rn[1] + rn[2] + rn[3];
                    sd = rd[0] + rd[1] + rd[2] + rd[3]; }
    for (int i = tid; i < NBLK - 1; i += TPB) {
        const unsigned long long* rec = ws + 2u * i;
        unsigned long long a, d;
        for (;;) {
            a = __hip_atomic_load(rec + 0, __ATOMIC_RELAXED, __HIP_MEMORY_SCOPE_AGENT);
            d = __hip_atomic_load(rec + 1, __ATOMIC_RELAXED, __HIP_MEMORY_SCOPE_AGENT);
            if (((unsigned int)(a >> 32) == ~(unsigned int)a) &&
                ((unsigned int)(d >> 32) == ~(unsigned int)d)) break;
            __builtin_amdgcn_s_sleep(1);   // be polite while other blocks finish
        }
        sn += __uint_as_float((unsigned int)a);
        sd += __uint_as_float((unsigned int)d);
    }
    __syncthreads();   // tid0's rn/rd reads done before LDS reuse below
#pragma unroll
    for (int off = 32; off > 0; off >>= 1) {
        sn += __shfl_down(sn, off);
        sd += __shfl_down(sd, off);
    }
    if ((tid & 63) == 0) { rn[tid >> 6] = sn; rd[tid >> 6] = sd; }
    __syncthreads();
    if (tid == 0)
        out[0] = (rn[0] + rn[1] + rn[2] + rn[3]) /
                 (rd[0] + rd[1] + rd[2] + rd[3] + 1e-4f);
}

extern "C" void kernel_launch(void* const* d_in, const int* in_sizes, int n_in,
                              void* d_out, int out_size, void* d_ws, size_t ws_size,
                              hipStream_t stream) {
    const float* iou_pred = (const float*)d_in[0];
    const int*   mask     = (const int*)  d_in[1];
    // d_in[2] = ind (unused by the layer)
    const float* box_pred = (const float*)d_in[3];
    const float* box_gt   = (const float*)d_in[4];
    float*              out = (float*)d_out;
    unsigned long long* ws  = (unsigned long long*)d_ws;   // NBLK packed records

    iou_fused<<<NBLK, TPB, 0, stream>>>(iou_pred, mask, box_pred, box_gt, ws, out);
}

// Round 7
// 103.422 us; speedup vs baseline: 1.0156x; 1.0156x over previous
//
#include <hip/hip_runtime.h>
#include <math.h>

#define B_   4
#define H_   496
#define W_   496
#define HW_  (H_ * W_)
#define N_   (B_ * HW_)
#define TPB  256
#define NPT  4                    // consecutive elements per thread (vector loads)
#define EPB  (TPB * NPT)          // 1024 elements per block
#define NBLK (N_ / EPB)           // 961 exactly

static_assert(N_ % EPB == 0, "no tail");
static_assert(HW_ % NPT == 0, "thread quad must not straddle batch b");

// native clang vector types: __builtin_nontemporal_load requires these
// (HIP_vector_type float4/int4 are structs and are rejected).
typedef float f32x4 __attribute__((ext_vector_type(4)));
typedef int   i32x4 __attribute__((ext_vector_type(4)));

union F4 { f32x4 v; float a[4]; };
union I4 { i32x4 v; int   a[4]; };

// Clip segment (xk,yk)+t*(dx,dy), t in [0,1], against axis box [-hx,hx]x[-hy,hy].
// SELECT-FREE SLAB METHOD: ta=(-h-k)*r, tb=(h-k)*r; min/max routes the
// entering/exiting plane automatically for either direction sign, so the
// 8 cmp+cndmask pairs of the per-plane formulation vanish (~16 VALU vs ~42).
//   dx==+-0: r=+-inf -> ta,tb = -+inf when inside the slab (no constraint),
//   same-sign inf when outside (delta clamps to 0). Exact-boundary 0*inf NaN
//   is quietly dropped by IEEE fminf/fmaxf (same measure-zero caveat as
//   before). Products are bit-identical to the previous per-plane form; only
//   the clamp placement moves, and all clamp cases yield identical deltas.
__device__ __forceinline__ float edge_delta(float xk, float yk,
                                            float rdx, float rdy,
                                            float hx, float hy) {
    const float tax = (-hx - xk) * rdx, tbx = (hx - xk) * rdx;
    const float tay = (-hy - yk) * rdy, tby = (hy - yk) * rdy;
    const float t0 = fmaxf(fmaxf(fminf(tax, tbx), fminf(tay, tby)), 0.f);  // v_max3
    const float t1 = fminf(fminf(fmaxf(tax, tbx), fmaxf(tay, tby)), 1.f);  // v_min3
    return fmaxf(t1 - t0, 0.f);
}

// One element's IoU-loss terms from 7 pred + 7 gt params (gt-local-frame method).
__device__ __forceinline__ void iou_elem(
    float pax, float pay, float paz, float pdx, float pdy, float pdz, float pr,
    float gax, float gay, float gaz, float gdx, float gdy, float gdz, float gr,
    float ip, float m, float& num, float& den)
{
    float sp, cp; __sincosf(pr, &sp, &cp);
    float sg, cg; __sincosf(gr, &sg, &cg);
    const float cth = fmaf(cp, cg,  sp * sg);   // cos(pr-gr)
    const float sth = fmaf(sp, cg, -cp * sg);   // sin(pr-gr)
    const float wx = pax - gax, wy = pay - gay;
    const float cx = fmaf(cg, wx,  sg * wy);
    const float cy = fmaf(cg, wy, -sg * wx);

    const float phx = 0.5f * pdx, phy = 0.5f * pdy;
    const float ghx = 0.5f * gdx, ghy = 0.5f * gdy;

    // pred corners in gt frame: c + R(th)*([+,-,-,+]phx, [+,+,-,-]phy)
    const float a1 = cth * phx, b1 = sth * phx;
    const float a2 = sth * phy, b2 = cth * phy;
    const float e1 = a1 - a2, e2 = a1 + a2;
    const float f1 = b1 + b2, f2 = b1 - b2;
    const float px0 = cx + e1, py0 = cy + f1;
    const float px1 = cx - e2, py1 = cy - f2;
    const float px2 = cx - e1, py2 = cy - f1;
    const float px3 = cx + e2, py3 = cy + f2;

    const float ta1 = a1 + a1, tb1 = b1 + b1;
    const float ta2 = a2 + a2, tb2 = b2 + b2;
    const float ra1 = __builtin_amdgcn_rcpf(ta1);
    const float rb1 = __builtin_amdgcn_rcpf(tb1);
    const float ra2 = __builtin_amdgcn_rcpf(ta2);
    const float rb2 = __builtin_amdgcn_rcpf(tb2);

    // Half 1: pred edges vs gt box. Piece area = Delta * 0.5*cross(p_k, d_k).
    // Edge k direction d_k has reciprocal components passed directly (signed).
    float inter;
    {
        const float d0 = edge_delta(px0, py0, -ra1, -rb1, ghx, ghy);  // d=(-ta1,-tb1)
        const float d1 = edge_delta(px1, py1,  ra2, -rb2, ghx, ghy);  // d=( ta2,-tb2)
        const float d2 = edge_delta(px2, py2,  ra1,  rb1, ghx, ghy);  // d=( ta1, tb1)
        const float d3 = edge_delta(px3, py3, -ra2,  rb2, ghx, ghy);  // d=(-ta2, tb2)
        inter =        d0 * fmaf(a1, py0, -b1 * px0);
        inter = fmaf(  d1, -fmaf(b2, px1,  a2 * py1), inter);
        inter = fmaf(  d2,  fmaf(b1, px2, -a1 * py2), inter);
        inter = fmaf(  d3,  fmaf(b2, px3,  a2 * py3), inter);
    }

    // Half 2: gt edges vs pred box, t computed in pred's frame (t invariant);
    // each axis-aligned gt edge piece contributes ghx*ghy*Delta.
    {
        const float A  = cth * ghx, Dv = sth * ghx;
        const float Bq = sth * ghy, Ev = cth * ghy;
        const float Cc = fmaf(cth, cx,  sth * cy);
        const float Gf = fmaf(sth, cx, -cth * cy);
        const float g1 = A + Bq,  g2 = A - Bq;
        const float h1 = Ev - Dv, h2 = Ev + Dv;
        const float u0 =  g1 - Cc, v0 =  h1 + Gf;
        const float u1 = -g2 - Cc, v1 =  h2 + Gf;
        const float u2 = -g1 - Cc, v2 = -h1 + Gf;
        const float u3 =  g2 - Cc, v3 = -h2 + Gf;

        const float tA = A + A,   tD = Dv + Dv;
        const float tB = Bq + Bq, tE = Ev + Ev;
        const float rA = __builtin_amdgcn_rcpf(tA);
        const float rD = __builtin_amdgcn_rcpf(tD);
        const float rB = __builtin_amdgcn_rcpf(tB);
        const float rE = __builtin_amdgcn_rcpf(tE);

        float sq;
        sq  = edge_delta(u0, v0, -rA,  rD, phx, phy);  // d=(-tA, tD)
        sq += edge_delta(u1, v1, -rB, -rE, phx, phy);  // d=(-tB,-tE)
        sq += edge_delta(u2, v2,  rA, -rD, phx, phy);  // d=( tA,-tD)
        sq += edge_delta(u3, v3,  rB,  rE, phx, phy);  // d=( tB, tE)
        inter = fmaf(ghx * ghy, sq, inter);
    }

    const float za0 = paz - 0.5f * pdz, za1 = paz + 0.5f * pdz;
    const float zb0 = gaz - 0.5f * gdz, zb1 = gaz + 0.5f * gdz;
    const float zo  = fmaxf(fminf(za1, zb1) - fmaxf(za0, zb0), 0.f);
    const float iv  = inter * zo;
    const float va  = pdx * pdy * pdz;
    const float vb  = gdx * gdy * gdz;
    const float iou = __fdividef(iv, va + vb - iv + 1e-7f);
    const float target = 2.f * iou - 1.f;

    num = fmaf(m, fabsf(ip - target), num);
    den += m;
}

// Fused kernel: per-block partials published as self-validating records in ws,
// block NBLK-1 polls + finishes. Record i (2 x 64b): lo=(bits(num) | ~bits(num)<<32),
// hi=(bits(den) | ~bits(den)<<32). Validation low32==~high32 is impossible for
// any constant 32-bit poison pattern repeated across the word, so the
// garbage-initialized ws needs no init pass.
// Agent-scope atomics: per-XCD L2s are not coherent (guide G16).
//
// Measured-final structure (session ledger): direct AoS box_gt loads beat
// both block-wide (R4, +2.8us) and wave-private (R6, +1.3us) LDS staging;
// slab-clipped edge_delta (R5) is the best compute core; launch_bounds(256,4)
// + nt streams (R3) marginal but kept.
__global__ __launch_bounds__(TPB, 4) void iou_fused(
    const float* __restrict__ iou_pred,
    const int*   __restrict__ mask,
    const float* __restrict__ box_pred,   // [B,7,H,W]
    const float* __restrict__ box_gt,     // [B,H,W,7]
    unsigned long long* __restrict__ ws,  // [NBLK*2] packed records
    float* __restrict__ out)
{
    __shared__ float rn[4], rd[4];

    const int tid = threadIdx.x;
    const int n0  = (blockIdx.x * TPB + tid) * NPT;   // 4 consecutive elements
    const int b   = n0 / HW_;
    const int hw  = n0 - b * HW_;                     // NPT-aligned

    // ---- issue ALL global loads upfront (16 x 16B in flight) ----
    // box_pred / iou_pred / mask: dense wave-coalesced single-touch streams ->
    // nontemporal. box_gt: AoS 112B-lane-stride, lines reused across its 7
    // loads -> keep cached (no nt).
    const float* bp = box_pred + (size_t)b * 7 * HW_ + hw;
    F4 pc[7];
#pragma unroll
    for (int c = 0; c < 7; ++c)
        pc[c].v = __builtin_nontemporal_load((const f32x4*)(bp + (size_t)c * HW_));

    float gtv[28];                                          // 7 aligned float4
    {
        const f32x4* g4 = (const f32x4*)(box_gt + (size_t)n0 * 7);
#pragma unroll
        for (int j = 0; j < 7; ++j)
            *(f32x4*)(gtv + 4 * j) = g4[j];
    }
    F4 ip4; ip4.v = __builtin_nontemporal_load((const f32x4*)(iou_pred + n0));
    I4 mk4; mk4.v = __builtin_nontemporal_load((const i32x4*)(mask + n0));

    // ---- compute 4 elements ----
    float num = 0.f, den = 0.f;
#pragma unroll
    for (int e = 0; e < NPT; ++e) {
        const float* g = gtv + 7 * e;
        iou_elem(pc[0].a[e], pc[1].a[e], pc[2].a[e],
                 pc[3].a[e], pc[4].a[e], pc[5].a[e], pc[6].a[e],
                 g[0], g[1], g[2], g[3], g[4], g[5], g[6],
                 ip4.a[e], (float)mk4.a[e], num, den);
    }

    // ---- wave(64) then cross-wave reduction ----
#pragma unroll
    for (int off = 32; off > 0; off >>= 1) {
        num += __shfl_down(num, off);
        den += __shfl_down(den, off);
    }
    if ((tid & 63) == 0) { rn[tid >> 6] = num; rd[tid >> 6] = den; }
    __syncthreads();

    if (blockIdx.x != NBLK - 1) {
        // publish partial (device-visible, self-validating vs any constant poison)
        if (tid == 0) {
            const unsigned long long a = __float_as_uint(rn[0] + rn[1] + rn[2] + rn[3]);
            const unsigned long long d = __float_as_uint(rd[0] + rd[1] + rd[2] + rd[3]);
            unsigned long long* rec = ws + 2u * blockIdx.x;
            __hip_atomic_store(rec + 0, a | (~a << 32), __ATOMIC_RELAXED, __HIP_MEMORY_SCOPE_AGENT);
            __hip_atomic_store(rec + 1, d | (~d << 32), __ATOMIC_RELAXED, __HIP_MEMORY_SCOPE_AGENT);
        }
        return;
    }

    // ---- finalizer block: seed with own partial, poll the other NBLK-1 ----
    float sn = 0.f, sd = 0.f;
    if (tid == 0) { sn = rn[0] + rn[1] + rn[2] + rn[3];
                    sd = rd[0] + rd[1] + rd[2] + rd[3]; }
    for (int i = tid; i < NBLK - 1; i += TPB) {
        const unsigned long long* rec = ws + 2u * i;
        unsigned long long a, d;
        for (;;) {
            a = __hip_atomic_load(rec + 0, __ATOMIC_RELAXED, __HIP_MEMORY_SCOPE_AGENT);
            d = __hip_atomic_load(rec + 1, __ATOMIC_RELAXED, __HIP_MEMORY_SCOPE_AGENT);
            if (((unsigned int)(a >> 32) == ~(unsigned int)a) &&
                ((unsigned int)(d >> 32) == ~(unsigned int)d)) break;
            __builtin_amdgcn_s_sleep(1);   // be polite while other blocks finish
        }
        sn += __uint_as_float((unsigned int)a);
        sd += __uint_as_float((unsigned int)d);
    }
    __syncthreads();   // tid0's rn/rd reads done before LDS reuse below
#pragma unroll
    for (int off = 32; off > 0; off >>= 1) {
        sn += __shfl_down(sn, off);
        sd += __shfl_down(sd, off);
    }
    if ((tid & 63) == 0) { rn[tid >> 6] = sn; rd[tid >> 6] = sd; }
    __syncthreads();
    if (tid == 0)
        out[0] = (rn[0] + rn[1] + rn[2] + rn[3]) /
                 (rd[0] + rd[1] + rd[2] + rd[3] + 1e-4f);
}

extern "C" void kernel_launch(void* const* d_in, const int* in_sizes, int n_in,
                              void* d_out, int out_size, void* d_ws, size_t ws_size,
                              hipStream_t stream) {
    const float* iou_pred = (const float*)d_in[0];
    const int*   mask     = (const int*)  d_in[1];
    // d_in[2] = ind (unused by the layer)
    const float* box_pred = (const float*)d_in[3];
    const float* box_gt   = (const float*)d_in[4];
    float*              out = (float*)d_out;
    unsigned long long* ws  = (unsigned long long*)d_ws;   // NBLK packed records

    iou_fused<<<NBLK, TPB, 0, stream>>>(iou_pred, mask, box_pred, box_gt, ws, out);
}